// Round 8
// baseline (8490.896 us; speedup 1.0000x reference)
//
#include <hip/hip_runtime.h>

typedef __bf16 bf16x8 __attribute__((ext_vector_type(8)));
typedef float  f32x4  __attribute__((ext_vector_type(4)));
typedef unsigned short u16;
typedef unsigned int   u32;
typedef unsigned long long u64;

#define NB 128      // batch
#define NT 1024     // time steps
#define NF 128      // input features
#define NH 256      // hidden units
#define NG 1024     // 4*NH gate columns
#define M_ROWS (NB*NT)

// flags layout (u32 offsets). Regions plain-stored by fast chains are 256B
// (64-u32) per group so no two XCDs share a line.
#define FT1_OFF  0      // + g*64 + j   fast L1 tags (4 used of 64)
#define FT2_OFF  512    // + g*64 + j   fast L2 tags
#define C1_OFF   1024   // + g*16       agent L1 counters (R4 protocol)
#define C2_OFF   1152   // + g*16       agent L2 counters
#define PING_OFF 1280   // + g*64 + r   ping ring r=0..7 (plain-st/sc0-ld test)
#define REGX_OFF 1792   // + x*16       per-XCD arrival counters (agent)
#define REGC_OFF 1920   //              registration counter (agent)
#define ABRT_OFF 1936   // + g          chain abort (agent)
#define DONE_OFF 1952   // + g          chain join (agent)
#define FLAGS_N  2048

__device__ __forceinline__ u16 f2bf(float f) {
  union { float f; u32 u; } c; c.f = f;
  u32 u = c.u;
  return (u16)((u + 0x7fffu + ((u >> 16) & 1u)) >> 16);   // RNE
}
__device__ __forceinline__ float sigm(float x) { return 1.f / (1.f + __expf(-x)); }
__device__ __forceinline__ float tanh_(float x) { return 1.f - 2.f / (1.f + __expf(2.f * x)); }
__device__ __forceinline__ f32x4 mm(bf16x8 a, bf16x8 b, f32x4 c) {
  return __builtin_amdgcn_mfma_f32_16x16x32_bf16(a, b, c, 0, 0, 0);
}
__device__ __forceinline__ void vm0() { asm volatile("s_waitcnt vmcnt(0)" ::: "memory"); }
__device__ __forceinline__ void sb0() { __builtin_amdgcn_sched_barrier(0); }

// ---- agent primitives (MALL coherence point; HW-proven R4) ----
__device__ __forceinline__ u32 a_ld32(const u32* p) { return __hip_atomic_load((u32*)p, __ATOMIC_RELAXED, __HIP_MEMORY_SCOPE_AGENT); }
__device__ __forceinline__ u64 a_ld64(const u64* p) { return __hip_atomic_load((u64*)p, __ATOMIC_RELAXED, __HIP_MEMORY_SCOPE_AGENT); }
__device__ __forceinline__ void a_st32(u32* p, u32 v) { __hip_atomic_store(p, v, __ATOMIC_RELAXED, __HIP_MEMORY_SCOPE_AGENT); }
__device__ __forceinline__ void a_st64(u64* p, u64 v) { __hip_atomic_store(p, v, __ATOMIC_RELAXED, __HIP_MEMORY_SCOPE_AGENT); }
__device__ __forceinline__ void a_add32(u32* p, u32 v) { __hip_atomic_fetch_add(p, v, __ATOMIC_RELAXED, __HIP_MEMORY_SCOPE_AGENT); }
__device__ __forceinline__ u32 a_addret(u32* p, u32 v) { return __hip_atomic_fetch_add(p, v, __ATOMIC_RELAXED, __HIP_MEMORY_SCOPE_AGENT); }

// ---- fast intra-XCD primitives: PLAIN stores (write-through L1, allocate in
// the XCD-shared L2, write-back) + sc0 LOADS (bypass L1, read L2 truth).
// Producer vm0 = data committed in local L2. Verified per-chain by ping. ----
__device__ __forceinline__ void p_st64(u64* p, u64 v) {
  asm volatile("global_store_dwordx2 %0, %1, off" :: "v"(p), "v"(v) : "memory");
}
__device__ __forceinline__ void p_st32(u32* p, u32 v) {
  asm volatile("global_store_dword %0, %1, off" :: "v"(p), "v"(v) : "memory");
}
__device__ __forceinline__ u64 s_ld64(const u64* p) {
  u64 r; asm volatile("global_load_dwordx2 %0, %1, off sc0" : "=v"(r) : "v"(p) : "memory"); return r;
}
__device__ __forceinline__ u32 s_ld32w(const u32* p) {
  u32 r; asm volatile("global_load_dword %0, %1, off sc0\n\ts_waitcnt vmcnt(0)" : "=v"(r) : "v"(p) : "memory"); return r;
}

// agent poll (R4-exact): all threads, relentless
__device__ __forceinline__ bool poll_ge(u32* c, u32 target, long& budget) {
  while (a_ld32(c) < target) { if (--budget <= 0) return false; }
  asm volatile("" ::: "memory");
  return true;
}
// fast poll: 16B tag line (4 per-WG tags), all lanes same addr -> 1 req/wave
__device__ __forceinline__ bool poll4f(const u32* tg, u32 target, long& budget) {
  const u64* p = (const u64*)tg;
  for (;;) {
    u64 a = s_ld64(p), b = s_ld64(p + 1);
    vm0(); sb0();
    if ((u32)a >= target && (u32)(a >> 32) >= target &&
        (u32)b >= target && (u32)(b >> 32) >= target) break;
    if (--budget <= 0) return false;
  }
  asm volatile("" ::: "memory");
  return true;
}

// ---------------------------------------------------------------------------
__global__ void prep(u32* __restrict__ flags) {
  int i = blockIdx.x * 256 + threadIdx.x;
  if (i < FLAGS_N) flags[i] = 0;
}

// ---------------------------------------------------------------------------
// One layer's scan. Arithmetic identical to rounds 2-7 (absmax 9.77e-4).
// FAST: plain-store / sc0-load via the XCD-shared L2 (ping-verified).
// !FAST: R4-exact agent protocol (atomic data, 16 per-wave adds, all-thread
// relentless poll) — the proven 5.94 ms structure.
// ---------------------------------------------------------------------------
template<bool IS1, bool FAST>
__device__ void scan(const float* __restrict__ U, const float* __restrict__ W,
                     const float* __restrict__ bias, const float* __restrict__ xf,
                     u64* hseq, u64* h2, u32* flags, float* hlast,
                     int g, int j, float (*gl)[16][68])
{
  const int tid = threadIdx.x, lane = tid & 63, w = tid >> 6;
  const int l15 = lane & 15, l16 = lane >> 4;
  constexpr int KIN  = IS1 ? NF : NH;
  constexpr int KTIN = KIN / 32;
  const int colb = w * NH + j * 64;

  // Resident W frags (B-operand), K = KIN
  bf16x8 wfr[KTIN][4];
#pragma unroll
  for (int kt = 0; kt < KTIN; ++kt) {
    const int k0 = kt * 32 + l16 * 8;
#pragma unroll
    for (int nt = 0; nt < 4; ++nt) {
      const float* wp = W + (long)k0 * NG + colb + nt * 16 + l15;
      union { u16 s[8]; bf16x8 v; } cv;
#pragma unroll
      for (int e = 0; e < 8; ++e) cv.s[e] = f2bf(wp[(long)e * NG]);
      wfr[kt][nt] = cv.v;
    }
  }
  // Resident U frags (B-operand), K = NH
  bf16x8 ufr[8][4];
#pragma unroll
  for (int kt = 0; kt < 8; ++kt) {
    const int k0 = kt * 32 + l16 * 8;
#pragma unroll
    for (int nt = 0; nt < 4; ++nt) {
      const float* up = U + (long)k0 * NG + colb + nt * 16 + l15;
      union { u16 s[8]; bf16x8 v; } cv;
#pragma unroll
      for (int e = 0; e < 8; ++e) cv.s[e] = f2bf(up[(long)e * NG]);
      ufr[kt][nt] = cv.v;
    }
  }

  const int prow = tid & 15, ublk = tid >> 4;
  const int b = g * 16 + prow, ucol = j * 64 + ublk * 4;

  float bv[4][4];
#pragma unroll
  for (int gg = 0; gg < 4; ++gg)
#pragma unroll
    for (int q = 0; q < 4; ++q) bv[gg][q] = bias[gg * NH + ucol + q];

  u32* ft1 = flags + FT1_OFF + g * 64;
  u32* ft2 = flags + FT2_OFF + g * 64;
  u32* c1  = flags + C1_OFF  + g * 16;
  u32* c2  = flags + C2_OFF  + g * 16;
  u32* mytag = (IS1 ? ft1 : ft2) + j;
  const long abatch = (long)(g * 16 + l15) * NT;

  float cst[4] = {0.f, 0.f, 0.f, 0.f};
  long budget = FAST ? 1000000 : 20000000;
  bool dead = false;

  for (int t = 0; t < NT; ++t) {
    bf16x8 ax[KTIN];
    f32x4 acc[4] = {};

    if constexpr (IS1) {
      // ---- x loads + cvt + x@W MFMAs (ungated; overlaps the wait) ----
      const float* xp0 = xf + (abatch + t) * NF;
      f32x4 xraw[KTIN][2];
#pragma unroll
      for (int kt = 0; kt < KTIN; ++kt) {
        const float* xp = xp0 + kt * 32 + l16 * 8;
        xraw[kt][0] = *reinterpret_cast<const f32x4*>(xp);
        xraw[kt][1] = *reinterpret_cast<const f32x4*>(xp + 4);
      }
#pragma unroll
      for (int kt = 0; kt < KTIN; ++kt) {
        union { u16 s[8]; bf16x8 v; } cv;
#pragma unroll
        for (int e = 0; e < 4; ++e) {
          cv.s[e] = f2bf(xraw[kt][0][e]); cv.s[4 + e] = f2bf(xraw[kt][1][e]);
        }
        ax[kt] = cv.v;
      }
#pragma unroll
      for (int kt = 0; kt < KTIN; ++kt)
#pragma unroll
        for (int nt = 0; nt < 4; ++nt) acc[nt] = mm(ax[kt], wfr[kt][nt], acc[nt]);

      // ---- recurrence gate + h_{t-1} loads + U MFMAs ----
      if (t > 0) {
        if (!dead) {
          bool okp;
          if constexpr (FAST) okp = poll4f(ft1, (u32)t, budget);
          else                okp = poll_ge(c1, 16u * (u32)t, budget);
          if (!okp) dead = true;
        }
        const u64* hb = hseq + (abatch + (t - 1)) * 64;
        u64 hr[8][2];
#pragma unroll
        for (int kt = 0; kt < 8; ++kt) {
          if constexpr (FAST) {
            hr[kt][0] = s_ld64(hb + kt * 8 + l16 * 2);
            hr[kt][1] = s_ld64(hb + kt * 8 + l16 * 2 + 1);
          } else {
            hr[kt][0] = a_ld64(hb + kt * 8 + l16 * 2);
            hr[kt][1] = a_ld64(hb + kt * 8 + l16 * 2 + 1);
          }
        }
        if constexpr (FAST) { vm0(); sb0(); }
#pragma unroll
        for (int kt = 0; kt < 8; ++kt) {
          union { u64 q[2]; bf16x8 v; } cv;
          cv.q[0] = hr[kt][0]; cv.q[1] = hr[kt][1];
#pragma unroll
          for (int nt = 0; nt < 4; ++nt) acc[nt] = mm(cv.v, ufr[kt][nt], acc[nt]);
        }
      }
    } else {
      // ---- L2: ONE merged gate (feed >= t+1, rec >= t) ----
      if (!dead) {
        bool okp = true;
        if constexpr (FAST) {
          const u32 tF = (u32)(t + 1), tR = (u32)t;
          const u64* pa = (const u64*)ft1;
          const u64* pb = (const u64*)ft2;
          for (;;) {
            u64 a1 = s_ld64(pa), b1 = s_ld64(pa + 1);
            u64 a2 = s_ld64(pb), b2 = s_ld64(pb + 1);
            vm0(); sb0();
            bool okF = (u32)a1 >= tF && (u32)(a1 >> 32) >= tF &&
                       (u32)b1 >= tF && (u32)(b1 >> 32) >= tF;
            bool okR = t == 0 || ((u32)a2 >= tR && (u32)(a2 >> 32) >= tR &&
                                  (u32)b2 >= tR && (u32)(b2 >> 32) >= tR);
            if (okF && okR) break;
            if (--budget <= 0) { okp = false; break; }
          }
        } else {
          const u32 tF = 16u * (u32)(t + 1), tR = 16u * (u32)t;
          for (;;) {
            u32 v1 = a_ld32(c1);
            u32 v2 = (t > 0) ? a_ld32(c2) : tR;
            if (v1 >= tF && v2 >= tR) break;
            if (--budget <= 0) { okp = false; break; }
          }
        }
        if (!okp) dead = true;
        asm volatile("" ::: "memory");
      }

      // ---- feed (hseq[t]) + recurrence (h2) loads issued together ----
      const u64* xb = hseq + (abatch + t) * 64;
      u64 xr[KTIN][2];
#pragma unroll
      for (int kt = 0; kt < KTIN; ++kt) {
        if constexpr (FAST) {
          xr[kt][0] = s_ld64(xb + kt * 8 + l16 * 2);
          xr[kt][1] = s_ld64(xb + kt * 8 + l16 * 2 + 1);
        } else {
          xr[kt][0] = a_ld64(xb + kt * 8 + l16 * 2);
          xr[kt][1] = a_ld64(xb + kt * 8 + l16 * 2 + 1);
        }
      }
      u64 hr[8][2];
      if (t > 0) {
        const u64* hb = h2 + ((((long)((t + 1) & 1) * 8 + g) * 16) + l15) * 64;
#pragma unroll
        for (int kt = 0; kt < 8; ++kt) {
          if constexpr (FAST) {
            hr[kt][0] = s_ld64(hb + kt * 8 + l16 * 2);
            hr[kt][1] = s_ld64(hb + kt * 8 + l16 * 2 + 1);
          } else {
            hr[kt][0] = a_ld64(hb + kt * 8 + l16 * 2);
            hr[kt][1] = a_ld64(hb + kt * 8 + l16 * 2 + 1);
          }
        }
      }
      if constexpr (FAST) { vm0(); sb0(); }
#pragma unroll
      for (int kt = 0; kt < KTIN; ++kt) {
        union { u64 q[2]; bf16x8 v; } cv;
        cv.q[0] = xr[kt][0]; cv.q[1] = xr[kt][1];
        ax[kt] = cv.v;
      }
#pragma unroll
      for (int kt = 0; kt < KTIN; ++kt)
#pragma unroll
        for (int nt = 0; nt < 4; ++nt) acc[nt] = mm(ax[kt], wfr[kt][nt], acc[nt]);
      if (t > 0) {
#pragma unroll
        for (int kt = 0; kt < 8; ++kt) {
          union { u64 q[2]; bf16x8 v; } cv;
          cv.q[0] = hr[kt][0]; cv.q[1] = hr[kt][1];
#pragma unroll
          for (int nt = 0; nt < 4; ++nt) acc[nt] = mm(cv.v, ufr[kt][nt], acc[nt]);
        }
      }
    }

    // ---- gate tiles -> LDS (cross-wave exchange) ----
#pragma unroll
    for (int nt = 0; nt < 4; ++nt)
#pragma unroll
      for (int r = 0; r < 4; ++r)
        gl[w][l16 * 4 + r][nt * 16 + l15] = acc[nt][r];
    __syncthreads();

    // ---- pointwise cell update (Keras order i, f, cbar, o) ----
    f32x4 gi = *reinterpret_cast<const f32x4*>(&gl[0][prow][ublk * 4]);
    f32x4 gf = *reinterpret_cast<const f32x4*>(&gl[1][prow][ublk * 4]);
    f32x4 gc = *reinterpret_cast<const f32x4*>(&gl[2][prow][ublk * 4]);
    f32x4 go = *reinterpret_cast<const f32x4*>(&gl[3][prow][ublk * 4]);
    float hh[4];
#pragma unroll
    for (int q = 0; q < 4; ++q) {
      float iv = sigm(gi[q] + bv[0][q]);
      float fv = sigm(gf[q] + bv[1][q]);
      float cd = tanh_(gc[q] + bv[2][q]);
      float ov = sigm(go[q] + bv[3][q]);
      cst[q] = fv * cst[q] + iv * cd;
      hh[q] = ov * tanh_(cst[q]);
    }
    union { u16 s[4]; u64 q; } hp;
#pragma unroll
    for (int q = 0; q < 4; ++q) hp.s[q] = f2bf(hh[q]);

    // ---- publish h_t ----
    u64* hw;
    if constexpr (IS1) hw = hseq + ((long)b * NT + t) * 64 + (ucol >> 2);
    else               hw = h2 + ((((long)(t & 1) * 8 + g) * 16) + prow) * 64 + (ucol >> 2);
    if constexpr (FAST) p_st64(hw, hp.q); else a_st64(hw, hp.q);
    if constexpr (!IS1) {
      if (t == NT - 1)
        *reinterpret_cast<f32x4*>(hlast + (long)b * NH + ucol) =
            f32x4{hh[0], hh[1], hh[2], hh[3]};
    }

    // ---- completion signal ----
    if constexpr (FAST) {
      vm0();               // data committed in local L2
      __syncthreads();     // all 4 waves done (also protects gl reuse)
      if (tid == 0) p_st32(mytag, (u32)(t + 1));
    } else {
      vm0();               // R4-exact: per-wave lane0 add, no extra barrier
      if (lane == 0) a_add32(IS1 ? c1 : c2, 1u);
      // gl WAR-safe via poll gating (R4-proven).
    }
  }
}

// ---------------------------------------------------------------------------
__global__ __launch_bounds__(256, 1) void lstm_fused(
    const float* __restrict__ x,
    const float* __restrict__ W1, const float* __restrict__ U1, const float* __restrict__ b1,
    const float* __restrict__ W2, const float* __restrict__ U2, const float* __restrict__ b2,
    u64* hseq, u64* h2, u32* flags, float* hlast)
{
  __shared__ __align__(16) float gl[4][16][68];
  __shared__ u32 planS;
  const int tid = threadIdx.x;

  // ---- phase 1: registration against ACTUAL placement (agent; R6-proven) ----
  if (tid == 0) {
    u32 xcc = 0;
    asm volatile("s_getreg_b32 %0, hwreg(HW_REG_XCC_ID)" : "=s"(xcc));
    xcc &= 7u;
    u32 slot = a_addret(flags + REGX_OFF + xcc * 16, 1u);
    vm0();
    a_add32(flags + REGC_OFF, 1u);
    long bud = 50000000; bool ok = true;
    while (a_ld32(flags + REGC_OFF) < 64u) { if (--bud <= 0) { ok = false; break; } }
    asm volatile("" ::: "memory");
    u32 grp, role, fast = 0;
    if (ok) {
      u32 nx[8], full[8], F = 0;
#pragma unroll
      for (int y = 0; y < 8; ++y) { nx[y] = a_ld32(flags + REGX_OFF + y * 16); full[y] = nx[y] >> 3; F += full[y]; }
      u32 cbase = 0, sbase = 0;
      for (u32 y = 0; y < xcc; ++y) { cbase += full[y]; sbase += nx[y] - 8u * full[y]; }
      if (slot < 8u * full[xcc]) {            // member of a formed local chain
        fast = 1u; grp = cbase + (slot >> 3); role = slot & 7u;
      } else {                                 // spare -> covers leftover group
        u32 si = sbase + (slot - 8u * full[xcc]);
        grp = F + (si >> 3); role = si & 7u;
      }
      if (grp > 7u) { grp &= 7u; fast = 0u; }  // safety clamp (unreachable)
    } else {
      grp = blockIdx.x & 7u;
      role = ((blockIdx.x >> 3) & 3u) + (blockIdx.x >= 32 ? 4u : 0u);
    }
    planS = fast | (grp << 1) | (role << 4);
  }
  __syncthreads();
  u32 plan = planS;
  bool fast = plan & 1u;
  const int g = (plan >> 1) & 7, role = (plan >> 4) & 7;
  const bool is1 = role < 4;
  const int j = role & 3;

  // ---- phase 2: ping-ring over the NEW primitive pair (plain-st/sc0-ld) ----
  if (fast) {
    if (tid == 0) {
      bool fail = false;
      u32* ping = flags + PING_OFF + g * 64;
      u32* slotp = ping + role;
      u32* prevp = ping + ((role + 7) & 7);
      for (u32 k = 1; k <= 2u && !fail; ++k) {
        if (role == 0) {
          p_st32(slotp, k); vm0();
          long pb = 20000;
          while (s_ld32w(prevp) < k) { if (--pb <= 0) { fail = true; break; } }
        } else {
          long pb = 20000;
          while (s_ld32w(prevp) < k) { if (--pb <= 0) { fail = true; break; } }
          if (!fail) { p_st32(slotp, k); vm0(); }
        }
      }
      if (fail) a_st32(flags + ABRT_OFF + g, 1u);
      vm0();
      a_add32(flags + DONE_OFF + g, 1u);
      long db = 20000000; bool jok = true;
      while (a_ld32(flags + DONE_OFF + g) < 8u) { if (--db <= 0) { jok = false; break; } }
      asm volatile("" ::: "memory");
      if (!jok || a_ld32(flags + ABRT_OFF + g) != 0u) planS = plan & ~1u;
    }
    __syncthreads();
    plan = planS; fast = plan & 1u;
  }

  // ---- phase 3: the scans (mode chain-uniform; groups independent) ----
  if (is1) {
    if (fast) scan<true,  true >(U1, W1, b1, x, hseq, h2, flags, hlast, g, j, gl);
    else      scan<true,  false>(U1, W1, b1, x, hseq, h2, flags, hlast, g, j, gl);
  } else {
    if (fast) scan<false, true >(U2, W2, b2, nullptr, hseq, h2, flags, hlast, g, j, gl);
    else      scan<false, false>(U2, W2, b2, nullptr, hseq, h2, flags, hlast, g, j, gl);
  }
}

// ---------------------------------------------------------------------------
__global__ void dense_out(const float* __restrict__ hl, const float* __restrict__ Wd,
                          const float* __restrict__ bd, float* __restrict__ out) {
  int b = blockIdx.x, l = threadIdx.x;
  f32x4 h  = *reinterpret_cast<const f32x4*>(hl + (long)b * NH + l * 4);
  f32x4 wv = *reinterpret_cast<const f32x4*>(Wd + l * 4);
  float s = h[0] * wv[0] + h[1] * wv[1] + h[2] * wv[2] + h[3] * wv[3];
#pragma unroll
  for (int off = 32; off > 0; off >>= 1) s += __shfl_down(s, off);
  if (l == 0) out[b] = fmaxf(s + bd[0], 0.f);
}

// ---------------------------------------------------------------------------
extern "C" void kernel_launch(void* const* d_in, const int* in_sizes, int n_in,
                              void* d_out, int out_size, void* d_ws, size_t ws_size,
                              hipStream_t stream) {
  const float* x  = (const float*)d_in[0];
  const float* W1 = (const float*)d_in[1];
  const float* U1 = (const float*)d_in[2];
  const float* b1 = (const float*)d_in[3];
  const float* W2 = (const float*)d_in[4];
  const float* U2 = (const float*)d_in[5];
  const float* b2 = (const float*)d_in[6];
  const float* Wd = (const float*)d_in[7];
  const float* bd = (const float*)d_in[8];
  float* out = (float*)d_out;

  char* ws = (char*)d_ws;
  size_t off = 0;
  auto alloc = [&](size_t bytes) -> char* {
    char* p = ws + off;
    off = (off + bytes + 255) & ~(size_t)255;
    return p;
  };
  u64*   hseq  = (u64*)  alloc((size_t)M_ROWS * NH * 2);       // 64 MiB
  u64*   h2    = (u64*)  alloc((size_t)2 * 8 * 16 * NH * 2);   // 128 KiB
  float* hlast = (float*)alloc((size_t)NB * NH * 4);           // 128 KiB
  u32*   flags = (u32*)  alloc(FLAGS_N * 4);                   // 8 KiB

  if (off > ws_size) {
    // workspace too small: finite sentinel 0x42424242 ~= 48.56 (NOT NaN)
    hipMemsetAsync(d_out, 0x42, (size_t)out_size * sizeof(float), stream);
    return;
  }

  prep<<<8, 256, 0, stream>>>(flags);
  lstm_fused<<<64, 256, 0, stream>>>(x, W1, U1, b1, W2, U2, b2, hseq, h2, flags, hlast);
  dense_out<<<128, 64, 0, stream>>>(hlast, Wd, bd, out);
}

// Round 9
// 5690.363 us; speedup vs baseline: 1.4922x; 1.4922x over previous
//
#include <hip/hip_runtime.h>

typedef __bf16 bf16x8 __attribute__((ext_vector_type(8)));
typedef float  f32x4  __attribute__((ext_vector_type(4)));
typedef unsigned short u16;
typedef unsigned int   u32;
typedef unsigned long long u64;

#define NB 128      // batch
#define NT 1024     // time steps
#define NF 128      // input features
#define NH 256      // hidden units
#define NG 1024     // 4*NH gate columns
#define M_ROWS (NB*NT)
#define SENT (~0ull)   // sentinel: 4x bf16 0xFFFF (NaN) -- unreachable as h data

__device__ __forceinline__ u16 f2bf(float f) {
  union { float f; u32 u; } c; c.f = f;
  u32 u = c.u;
  return (u16)((u + 0x7fffu + ((u >> 16) & 1u)) >> 16);   // RNE
}
__device__ __forceinline__ float sigm(float x) { return 1.f / (1.f + __expf(-x)); }
__device__ __forceinline__ float tanh_(float x) { return 1.f - 2.f / (1.f + __expf(2.f * x)); }
__device__ __forceinline__ f32x4 mm(bf16x8 a, bf16x8 b, f32x4 c) {
  return __builtin_amdgcn_mfma_f32_16x16x32_bf16(a, b, c, 0, 0, 0);
}

// Relaxed AGENT atomics: MALL coherence point by scope, no cache-maintenance.
// (HW-proven data path, rounds 4-8.)
__device__ __forceinline__ u64 a_ld64(const u64* p) { return __hip_atomic_load((u64*)p, __ATOMIC_RELAXED, __HIP_MEMORY_SCOPE_AGENT); }
__device__ __forceinline__ void a_st64(u64* p, u64 v) { __hip_atomic_store(p, v, __ATOMIC_RELAXED, __HIP_MEMORY_SCOPE_AGENT); }

// ---------------------------------------------------------------------------
// prep: sentinel-fill hseq (64 MiB) + h2 (256 KiB) at the MALL coherence
// point. Runs every launch -> also erases stale data from prior replays.
// ---------------------------------------------------------------------------
__global__ void prep(u64* __restrict__ hseq, u64* __restrict__ h2) {
  long i = (long)blockIdx.x * 256 + threadIdx.x;
  if (i < (long)M_ROWS * 64) a_st64(hseq + i, SENT);
  if (i < 4L * 8 * 16 * 64)  a_st64(h2 + i, SENT);
}

// ---------------------------------------------------------------------------
// Fused 2-layer LSTM scan, SENTINEL protocol (no counters, no tags, no vm0
// on the producer critical path):
//   producer: a_st64 h chunks, fire-and-forget.
//   consumer: poll the data words themselves until != SENT; the detecting
//             load IS the data load (1 RT instead of ack+add+detect+load).
// Buffers: hseq [NB,NT,NH] bf16 write-once (L1 rec + L1->L2 feed);
//          h2 4-deep [4][8][16][NH] bf16 (L2 rec). At step t each L2 WG
//          re-sentinels its chunk of slot (t+1)&3 (holds t-3 data, whose
//          readers -- step t-2 -- are provably done once h_{t-1} is seen).
// 64 WGs: bid<32 -> L1, else L2; 8 groups x 4 WGs x 4 waves (wave = gate).
// Frags pinned in VGPRs via asm "+v" (defeat remat-by-reload each step).
// ---------------------------------------------------------------------------
template<bool IS1>
__device__ void scan(const float* __restrict__ U, const float* __restrict__ W,
                     const float* __restrict__ bias, const float* __restrict__ xf,
                     u64* hseq, u64* h2, float* hlast,
                     int g, int j, float (*gl)[16][68])
{
  const int tid = threadIdx.x, lane = tid & 63, w = tid >> 6;
  const int l15 = lane & 15, l16 = lane >> 4;
  constexpr int KIN  = IS1 ? NF : NH;
  constexpr int KTIN = KIN / 32;
  const int colb = w * NH + j * 64;

  // Resident W frags (B-operand), K = KIN
  bf16x8 wfr[KTIN][4];
#pragma unroll
  for (int kt = 0; kt < KTIN; ++kt) {
    const int k0 = kt * 32 + l16 * 8;
#pragma unroll
    for (int nt = 0; nt < 4; ++nt) {
      const float* wp = W + (long)k0 * NG + colb + nt * 16 + l15;
      union { u16 s[8]; bf16x8 v; } cv;
#pragma unroll
      for (int e = 0; e < 8; ++e) cv.s[e] = f2bf(wp[(long)e * NG]);
      wfr[kt][nt] = cv.v;
    }
  }
  // Resident U frags (B-operand), K = NH
  bf16x8 ufr[8][4];
#pragma unroll
  for (int kt = 0; kt < 8; ++kt) {
    const int k0 = kt * 32 + l16 * 8;
#pragma unroll
    for (int nt = 0; nt < 4; ++nt) {
      const float* up = U + (long)k0 * NG + colb + nt * 16 + l15;
      union { u16 s[8]; bf16x8 v; } cv;
#pragma unroll
      for (int e = 0; e < 8; ++e) cv.s[e] = f2bf(up[(long)e * NG]);
      ufr[kt][nt] = cv.v;
    }
  }
  // Pin frags: values become opaque -> compiler cannot re-derive them by
  // re-loading U/W from memory inside the loop (VGPR_Count 164-196 in prior
  // rounds proves it was doing exactly that).
#pragma unroll
  for (int kt = 0; kt < KTIN; ++kt)
#pragma unroll
    for (int nt = 0; nt < 4; ++nt)
      asm volatile("" : "+v"(wfr[kt][nt]));
#pragma unroll
  for (int kt = 0; kt < 8; ++kt)
#pragma unroll
    for (int nt = 0; nt < 4; ++nt)
      asm volatile("" : "+v"(ufr[kt][nt]));

  const int prow = tid & 15, ublk = tid >> 4;
  const int b = g * 16 + prow, ucol = j * 64 + ublk * 4;

  float bv[4][4];
#pragma unroll
  for (int gg = 0; gg < 4; ++gg)
#pragma unroll
    for (int q = 0; q < 4; ++q) bv[gg][q] = bias[gg * NH + ucol + q];

  const long abatch = (long)(g * 16 + l15) * NT;

  float cst[4] = {0.f, 0.f, 0.f, 0.f};
  long budget = 500000;   // poll iterations (~1 us each); bail, never hang

  for (int t = 0; t < NT; ++t) {
    bf16x8 ax[KTIN];
    f32x4 acc[4] = {};

    if constexpr (IS1) {
      // ---- x loads + cvt + x@W MFMAs (overlaps producers' store flight) ----
      const float* xp0 = xf + (abatch + t) * NF;
      f32x4 xraw[KTIN][2];
#pragma unroll
      for (int kt = 0; kt < KTIN; ++kt) {
        const float* xp = xp0 + kt * 32 + l16 * 8;
        xraw[kt][0] = *reinterpret_cast<const f32x4*>(xp);
        xraw[kt][1] = *reinterpret_cast<const f32x4*>(xp + 4);
      }
#pragma unroll
      for (int kt = 0; kt < KTIN; ++kt) {
        union { u16 s[8]; bf16x8 v; } cv;
#pragma unroll
        for (int e = 0; e < 4; ++e) {
          cv.s[e] = f2bf(xraw[kt][0][e]); cv.s[4 + e] = f2bf(xraw[kt][1][e]);
        }
        ax[kt] = cv.v;
      }
#pragma unroll
      for (int kt = 0; kt < KTIN; ++kt)
#pragma unroll
        for (int nt = 0; nt < 4; ++nt) acc[nt] = mm(ax[kt], wfr[kt][nt], acc[nt]);

      // ---- sentinel-poll h_{t-1} (detect == data) + U MFMAs ----
      if (t > 0) {
        const u64* hb = hseq + (abatch + (t - 1)) * 64;
        u64 hr[8][2];
        for (;;) {
          bool ok = true;
#pragma unroll
          for (int kt = 0; kt < 8; ++kt) {
            hr[kt][0] = a_ld64(hb + kt * 8 + l16 * 2);
            hr[kt][1] = a_ld64(hb + kt * 8 + l16 * 2 + 1);
          }
#pragma unroll
          for (int kt = 0; kt < 8; ++kt)
            ok = ok && (hr[kt][0] != SENT) && (hr[kt][1] != SENT);
          if (__all(ok ? 1 : 0)) break;
          if (--budget <= 0) break;
        }
        asm volatile("" ::: "memory");
#pragma unroll
        for (int kt = 0; kt < 8; ++kt) {
          union { u64 q[2]; bf16x8 v; } cv;
          cv.q[0] = hr[kt][0]; cv.q[1] = hr[kt][1];
#pragma unroll
          for (int nt = 0; nt < 4; ++nt) acc[nt] = mm(cv.v, ufr[kt][nt], acc[nt]);
        }
      }
    } else {
      // ---- L2: ONE sentinel-poll over feed (hseq[t]) + rec (h2 slot) ----
      const u64* xb = hseq + (abatch + t) * 64;
      const u64* hb = h2 + (((long)((t + 3) & 3) * 8 + g) * 16 + l15) * 64;
      u64 xr[8][2], hr[8][2];
      for (;;) {
        bool ok = true;
#pragma unroll
        for (int kt = 0; kt < 8; ++kt) {
          xr[kt][0] = a_ld64(xb + kt * 8 + l16 * 2);
          xr[kt][1] = a_ld64(xb + kt * 8 + l16 * 2 + 1);
        }
#pragma unroll
        for (int kt = 0; kt < 8; ++kt)
          ok = ok && (xr[kt][0] != SENT) && (xr[kt][1] != SENT);
        if (t > 0) {
#pragma unroll
          for (int kt = 0; kt < 8; ++kt) {
            hr[kt][0] = a_ld64(hb + kt * 8 + l16 * 2);
            hr[kt][1] = a_ld64(hb + kt * 8 + l16 * 2 + 1);
          }
#pragma unroll
          for (int kt = 0; kt < 8; ++kt)
            ok = ok && (hr[kt][0] != SENT) && (hr[kt][1] != SENT);
        }
        if (__all(ok ? 1 : 0)) break;
        if (--budget <= 0) break;
      }
      asm volatile("" ::: "memory");
#pragma unroll
      for (int kt = 0; kt < KTIN; ++kt) {
        union { u64 q[2]; bf16x8 v; } cv;
        cv.q[0] = xr[kt][0]; cv.q[1] = xr[kt][1];
        ax[kt] = cv.v;
      }
#pragma unroll
      for (int kt = 0; kt < KTIN; ++kt)
#pragma unroll
        for (int nt = 0; nt < 4; ++nt) acc[nt] = mm(ax[kt], wfr[kt][nt], acc[nt]);
      if (t > 0) {
#pragma unroll
        for (int kt = 0; kt < 8; ++kt) {
          union { u64 q[2]; bf16x8 v; } cv;
          cv.q[0] = hr[kt][0]; cv.q[1] = hr[kt][1];
#pragma unroll
          for (int nt = 0; nt < 4; ++nt) acc[nt] = mm(cv.v, ufr[kt][nt], acc[nt]);
        }
      }
    }

    // ---- gate tiles -> LDS (cross-wave exchange); 2 barriers protect gl
    // (the old counter-gating no longer orders waves within a WG) ----
#pragma unroll
    for (int nt = 0; nt < 4; ++nt)
#pragma unroll
      for (int r = 0; r < 4; ++r)
        gl[w][l16 * 4 + r][nt * 16 + l15] = acc[nt][r];
    __syncthreads();
    f32x4 gi = *reinterpret_cast<const f32x4*>(&gl[0][prow][ublk * 4]);
    f32x4 gf = *reinterpret_cast<const f32x4*>(&gl[1][prow][ublk * 4]);
    f32x4 gc = *reinterpret_cast<const f32x4*>(&gl[2][prow][ublk * 4]);
    f32x4 go = *reinterpret_cast<const f32x4*>(&gl[3][prow][ublk * 4]);
    __syncthreads();

    // ---- pointwise cell update (Keras order i, f, cbar, o) ----
    float hh[4];
#pragma unroll
    for (int q = 0; q < 4; ++q) {
      float iv = sigm(gi[q] + bv[0][q]);
      float fv = sigm(gf[q] + bv[1][q]);
      float cd = tanh_(gc[q] + bv[2][q]);
      float ov = sigm(go[q] + bv[3][q]);
      cst[q] = fv * cst[q] + iv * cd;
      hh[q] = ov * tanh_(cst[q]);
    }
    union { u16 s[4]; u64 q; } hp;
#pragma unroll
    for (int q = 0; q < 4; ++q) hp.s[q] = f2bf(hh[q]);

    // ---- publish h_t: fire-and-forget atomic store (no vm0, no signal) ----
    if constexpr (IS1) {
      a_st64(hseq + ((long)b * NT + t) * 64 + (ucol >> 2), hp.q);
    } else {
      a_st64(h2 + (((long)(t & 3) * 8 + g) * 16 + prow) * 64 + (ucol >> 2), hp.q);
      // wipe own chunk of slot (t+1)&3 (holds t-3 data; readers done).
      // Next write to that slot (step t+1) is ordered behind this store by
      // the intervening poll's vmcnt(0) drain.
      a_st64(h2 + (((long)((t + 1) & 3) * 8 + g) * 16 + prow) * 64 + (ucol >> 2), SENT);
      if (t == NT - 1)
        *reinterpret_cast<f32x4*>(hlast + (long)b * NH + ucol) =
            f32x4{hh[0], hh[1], hh[2], hh[3]};
    }
  }
}

// ---------------------------------------------------------------------------
__global__ __launch_bounds__(256, 1) void lstm_fused(
    const float* __restrict__ x,
    const float* __restrict__ W1, const float* __restrict__ U1, const float* __restrict__ b1,
    const float* __restrict__ W2, const float* __restrict__ U2, const float* __restrict__ b2,
    u64* hseq, u64* h2, float* hlast)
{
  __shared__ __align__(16) float gl[4][16][68];
  const int bid = blockIdx.x;
  const int sb  = bid & 31, g = sb & 7, j = sb >> 3;
  if (bid < 32)
    scan<true >(U1, W1, b1, x, hseq, h2, nullptr, g, j, gl);
  else
    scan<false>(U2, W2, b2, nullptr, hseq, h2, hlast, g, j, gl);
}

// ---------------------------------------------------------------------------
__global__ void dense_out(const float* __restrict__ hl, const float* __restrict__ Wd,
                          const float* __restrict__ bd, float* __restrict__ out) {
  int b = blockIdx.x, l = threadIdx.x;
  f32x4 h  = *reinterpret_cast<const f32x4*>(hl + (long)b * NH + l * 4);
  f32x4 wv = *reinterpret_cast<const f32x4*>(Wd + l * 4);
  float s = h[0] * wv[0] + h[1] * wv[1] + h[2] * wv[2] + h[3] * wv[3];
#pragma unroll
  for (int off = 32; off > 0; off >>= 1) s += __shfl_down(s, off);
  if (l == 0) out[b] = fmaxf(s + bd[0], 0.f);
}

// ---------------------------------------------------------------------------
extern "C" void kernel_launch(void* const* d_in, const int* in_sizes, int n_in,
                              void* d_out, int out_size, void* d_ws, size_t ws_size,
                              hipStream_t stream) {
  const float* x  = (const float*)d_in[0];
  const float* W1 = (const float*)d_in[1];
  const float* U1 = (const float*)d_in[2];
  const float* b1 = (const float*)d_in[3];
  const float* W2 = (const float*)d_in[4];
  const float* U2 = (const float*)d_in[5];
  const float* b2 = (const float*)d_in[6];
  const float* Wd = (const float*)d_in[7];
  const float* bd = (const float*)d_in[8];
  float* out = (float*)d_out;

  char* ws = (char*)d_ws;
  size_t off = 0;
  auto alloc = [&](size_t bytes) -> char* {
    char* p = ws + off;
    off = (off + bytes + 255) & ~(size_t)255;
    return p;
  };
  u64*   hseq  = (u64*)  alloc((size_t)M_ROWS * NH * 2);       // 64 MiB
  u64*   h2    = (u64*)  alloc((size_t)4 * 8 * 16 * NH * 2);   // 256 KiB
  float* hlast = (float*)alloc((size_t)NB * NH * 4);           // 128 KiB

  if (off > ws_size) {
    // workspace too small: finite sentinel 0x42424242 ~= 48.56 (NOT NaN)
    hipMemsetAsync(d_out, 0x42, (size_t)out_size * sizeof(float), stream);
    return;
  }

  prep<<<32768, 256, 0, stream>>>(hseq, h2);
  lstm_fused<<<64, 256, 0, stream>>>(x, W1, U1, b1, W2, U2, b2, hseq, h2, hlast);
  dense_out<<<128, 64, 0, stream>>>(hlast, Wd, bd, out);
}